// Round 8
// baseline (484.256 us; speedup 1.0000x reference)
//
#include <hip/hip_runtime.h>
#include <hip/hip_cooperative_groups.h>

typedef unsigned long long u64;
typedef unsigned int u32;

#define BATCH 16
#define NANCH 25200
#define NCLS 80
#define NFEAT 85
#define TOPK 1024
#define MAXDET 300
#define CONF_T 0.25f
#define IOU_T 0.45f
#define MAX_WH 7680.0f

#define GRP 16                    // anchors per wave-group
#define GRPB (GRP * NFEAT * 4)    // 5440 B, 16B-aligned (16*340)
#define NGRP (NANCH / GRP)        // 1575 exact

// async 16B global->LDS (gfx950); divergent-exec tail proven safe R0-R7.
__device__ __forceinline__ void gload_lds16(const void* g, void* l) {
    __builtin_amdgcn_global_load_lds(
        (const __attribute__((address_space(1))) unsigned int*)g,
        (__attribute__((address_space(3))) unsigned int*)l, 16, 0, 0);
}

// ---------------------------------------------------------------------------
// K1: per-anchor score + key (per-wave DMA structure, proven R5-R7).
// R8: 2100 blocks = 8400 waves x exactly 3 groups (perfect balance; 2048
// blocks had a 3-vs-4 iteration straggler tail).
// ---------------------------------------------------------------------------
__global__ __launch_bounds__(256) void score_kernel(const float* __restrict__ in,
                                                    u64* __restrict__ keys,
                                                    float* __restrict__ out) {
    __shared__ char lds[4 * GRPB];   // 21760 B, one 5440B slice per wave
    const int tid = threadIdx.x, wv = tid >> 6, lane = tid & 63;
    if (blockIdx.x == 0 && tid == 0) { out[0] = 0.0f; out[1] = 0.0f; }
    char* myl = lds + wv * GRPB;
    const float* myp = (const float*)myl + (lane >> 2) * NFEAT;
    const int a = lane >> 2, q = lane & 3;
    const int wave_id = (blockIdx.x << 2) | wv;
    const int nwaves = gridDim.x << 2;                 // 8400
    for (int g = wave_id; g < BATCH * NGRP; g += nwaves) {
        const int b = g / NGRP;
        const int a0 = (g - b * NGRP) * GRP;
        const char* gbase = (const char*)(in + ((size_t)b * NANCH + a0) * NFEAT);
#pragma unroll
        for (int r = 0; r < 6; ++r) {
            const int myb = (r << 10) + lane * 16;
            if (myb < GRPB) gload_lds16(gbase + myb, myl + (r << 10));
        }
        asm volatile("s_waitcnt vmcnt(0)" ::: "memory");   // per-wave drain
        __builtin_amdgcn_sched_barrier(0);                 // no hoist past wait
        float obj = myp[4];
        float best = -1e30f;
        int bj = 0;
#pragma unroll
        for (int k = 0; k < 20; ++k) {
            float v = myp[5 + q * 20 + k] * obj;
            if (v > best) { best = v; bj = q * 20 + k; }
        }
#pragma unroll
        for (int d = 1; d < 4; d <<= 1) {
            float ob = __shfl_xor(best, d, 64);
            int oj = __shfl_xor(bj, d, 64);
            if (ob > best || (ob == best && oj < bj)) { best = ob; bj = oj; }
        }
        if (q == 0) {
            bool valid = (obj > CONF_T) && (best > CONF_T);
            float sc = valid ? best : -1.0f;
            u32 sb = __float_as_uint(sc);
            u32 ord = sb ^ ((sb & 0x80000000u) ? 0xFFFFFFFFu : 0x80000000u);
            int idx = a0 + a;
            keys[(size_t)b * NANCH + idx] =
                ((u64)ord << 32) | ((u64)((u32)(idx ^ 0xFFFF) & 0xFFFFu) << 8) | (u64)bj;
        }
    }
}

// ---------------------------------------------------------------------------
// Shared-memory phase structs (overlaid in the cooperative kernel).
// ---------------------------------------------------------------------------
struct SmemS {
    u32 wcnt[16][17];
    u32 tot[17];
    u32 s_prefix12, s_cnt;
    u64 buf[2048];
};
struct SmemI { float4 sbx[TOPK]; };
struct SmemN {
    u64 sM[TOPK * 16];      // 131072
    u64 kw[16];
    int wpfx[17];
    float sdet[MAXDET * 6];
    float s_sum, s_max;
};
union SmemU { SmemS s; SmemI i; SmemN n; };   // ~138.5 KB (< 160 KB/CU)

// ---------------------------------------------------------------------------
// Phase S: exact top-1024 per batch (R7-proven: ballot-hist + A/B compaction
// + hybrid bitonic sort + extraction). 1024 threads.
// ---------------------------------------------------------------------------
__device__ __forceinline__ void dev_select(int b, int tid, SmemS& sm,
                                           const u64* __restrict__ keys,
                                           const float* __restrict__ in,
                                           float4* __restrict__ box4,
                                           float4* __restrict__ boxoff4,
                                           float* __restrict__ score,
                                           float* __restrict__ cls,
                                           u64* __restrict__ vmask) {
    const int lane = tid & 63, wv = tid >> 6;
    const u64* kb = keys + (size_t)b * NANCH;
    const ulonglong2* kb2 = (const ulonglong2*)kb;    // 12600 pairs
    u64* buf = sm.buf;

    // phase 1: register ballot-histogram (support {0x407} U [0xBE8,0xBF7]).
    u32 myc = 0;
    for (int n = tid; n < 12600; n += 1024) {
        ulonglong2 kk = kb2[n];
        u32 b0 = (u32)(kk.x >> 52);
        u32 b1 = (u32)(kk.y >> 52);
        u32 c0 = (b0 == 0x407u) ? 16u : (b0 - 0xBE8u);
        u32 c1 = (b1 == 0x407u) ? 16u : (b1 - 0xBE8u);
#pragma unroll
        for (u32 k = 0; k < 17; ++k) {
            u64 m0 = __ballot(c0 == k);
            u64 m1 = __ballot(c1 == k);
            if (lane == (int)k) myc += (u32)__popcll(m0) + (u32)__popcll(m1);
        }
    }
    if (lane < 17) sm.wcnt[wv][lane] = myc;
    if (tid == 0) sm.s_cnt = 0u;
    __syncthreads();
    if (tid < 17) {
        u32 t = 0;
#pragma unroll
        for (int w = 0; w < 16; ++w) t += sm.wcnt[w][tid];
        sm.tot[tid] = t;
    }
    __syncthreads();
    if (tid == 0) {
        u32 acc = 0; u32 p = 0x407u;
        for (int k = 15; k >= 0; --k) {
            if (acc < (u32)TOPK && acc + sm.tot[k] >= (u32)TOPK) p = 0xBE8u + (u32)k;
            acc += sm.tot[k];
        }
        if (acc < (u32)TOPK) p = 0x407u;
        sm.s_prefix12 = p;
    }
    __syncthreads();
    const u32 p12 = sm.s_prefix12;
    // Pass A: strictly greater (count < 1024 by construction).
    for (int n = tid; n < 12600; n += 1024) {
        ulonglong2 kk = kb2[n];
        if ((u32)(kk.x >> 52) > p12) {
            u32 pos = atomicAdd(&sm.s_cnt, 1u);
            if (pos < 2048u) buf[pos] = kk.x;
        }
        if ((u32)(kk.y >> 52) > p12) {
            u32 pos = atomicAdd(&sm.s_cnt, 1u);
            if (pos < 2048u) buf[pos] = kk.y;
        }
    }
    __syncthreads();
    // Pass B: equal class (overflow drops only ==-class -> exact top-k).
    for (int n = tid; n < 12600; n += 1024) {
        ulonglong2 kk = kb2[n];
        if ((u32)(kk.x >> 52) == p12) {
            u32 pos = atomicAdd(&sm.s_cnt, 1u);
            if (pos < 2048u) buf[pos] = kk.x;
        }
        if ((u32)(kk.y >> 52) == p12) {
            u32 pos = atomicAdd(&sm.s_cnt, 1u);
            if (pos < 2048u) buf[pos] = kk.y;
        }
    }
    __syncthreads();
    u32 cnt = sm.s_cnt; if (cnt > 2048u) cnt = 2048u;
    for (int n = (int)cnt + tid; n < 2048; n += 1024) buf[n] = 0ull;
    __syncthreads();

    // hybrid bitonic sort, descending, 2048 keys.
    const int base = wv * 128;
    u64 r0 = buf[base + lane], r1 = buf[base + 64 + lane];
    for (int k2 = 2; k2 <= 128; k2 <<= 1) {
        const bool d0 = (((base + lane) & k2) == 0);
        const bool d1 = (((base + 64 + lane) & k2) == 0);
        for (int jj = (k2 >> 1); jj >= 1; jj >>= 1) {
            if (jj == 64) {
                u64 mx = r0 > r1 ? r0 : r1, mn = r0 > r1 ? r1 : r0;
                r0 = d0 ? mx : mn; r1 = d0 ? mn : mx;
            } else {
                const bool up = (lane & jj) != 0;
                u64 v0 = __shfl_xor(r0, jj, 64);
                u64 v1 = __shfl_xor(r1, jj, 64);
                const bool km0 = (d0 != up), km1 = (d1 != up);
                r0 = km0 ? (r0 > v0 ? r0 : v0) : (r0 < v0 ? r0 : v0);
                r1 = km1 ? (r1 > v1 ? r1 : v1) : (r1 < v1 ? r1 : v1);
            }
        }
    }
    for (int k2 = 256; k2 <= 2048; k2 <<= 1) {
        buf[base + lane] = r0; buf[base + 64 + lane] = r1;
        __syncthreads();
        for (int jj = (k2 >> 1); jj >= 128; jj >>= 1) {
            int i = ((tid & ~(jj - 1)) << 1) | (tid & (jj - 1));
            int part = i | jj;
            u64 a = buf[i], c = buf[part];
            bool sw = ((i & k2) == 0) ? (a < c) : (a > c);
            if (sw) { buf[i] = c; buf[part] = a; }
            __syncthreads();
        }
        r0 = buf[base + lane]; r1 = buf[base + 64 + lane];
        const bool d0 = (((base + lane) & k2) == 0);
        for (int jj = 64; jj >= 1; jj >>= 1) {
            if (jj == 64) {
                u64 mx = r0 > r1 ? r0 : r1, mn = r0 > r1 ? r1 : r0;
                r0 = d0 ? mx : mn; r1 = d0 ? mn : mx;
            } else {
                const bool up = (lane & jj) != 0;
                u64 v0 = __shfl_xor(r0, jj, 64);
                u64 v1 = __shfl_xor(r1, jj, 64);
                const bool km = (d0 != up);
                r0 = km ? (r0 > v0 ? r0 : v0) : (r0 < v0 ? r0 : v0);
                r1 = km ? (r1 > v1 ? r1 : v1) : (r1 < v1 ? r1 : v1);
            }
        }
    }
    buf[base + lane] = r0; buf[base + 64 + lane] = r1;
    __syncthreads();

    // extraction: rank tid.
    u64 k = buf[tid];
    u32 ord = (u32)(k >> 32);
    u32 sb = (ord & 0x80000000u) ? (ord ^ 0x80000000u) : ~ord;
    float sc = __uint_as_float(sb);
    int idx = (int)((((u32)(k >> 8)) & 0xFFFFu) ^ 0xFFFFu);
    int j = (int)(k & 0xFFu);
    const float* pr = in + ((size_t)b * NANCH + idx) * NFEAT;
    float cx = pr[0], cy = pr[1], ww = pr[2], hh = pr[3];
    float x1 = cx - ww / 2.0f, y1 = cy - hh / 2.0f;
    float x2 = cx + ww / 2.0f, y2 = cy + hh / 2.0f;
    float c = (float)j;
    float cm = c * MAX_WH;
    box4[b * TOPK + tid]    = make_float4(x1, y1, x2, y2);
    boxoff4[b * TOPK + tid] = make_float4(x1 + cm, y1 + cm, x2 + cm, y2 + cm);
    score[b * TOPK + tid] = sc;
    cls[b * TOPK + tid] = c;
    u64 bal = __ballot(sc > 0.0f);
    if ((tid & 63) == 0) vmask[b * 16 + (tid >> 6)] = bal;
}

// ---------------------------------------------------------------------------
// Phase N: greedy NMS + finalize (OR-tree fast path, proven R1-R7).
// stride = blockDim (512 standalone / 1024 coop).
// ---------------------------------------------------------------------------
__device__ __forceinline__ void dev_nms(int b, int tid, int stride, SmemN& sm,
                                        const u64* __restrict__ M,
                                        const u64* __restrict__ vmask,
                                        const float4* __restrict__ box4,
                                        const float* __restrict__ score,
                                        const float* __restrict__ cls,
                                        float* __restrict__ out) {
    {
        const ulonglong2* Ms = (const ulonglong2*)(M + (size_t)b * TOPK * 16);
        ulonglong2* Ldst = (ulonglong2*)sm.sM;
#pragma unroll 4
        for (int t = tid; t < TOPK * 8; t += stride) Ldst[t] = Ms[t];
    }
    for (int t = tid; t < MAXDET * 6; t += stride) sm.sdet[t] = 0.0f;
    if (tid == 0) { sm.s_sum = 0.0f; sm.s_max = 0.0f; }
    __syncthreads();
    if (tid < 16) {
        const int w = tid;
        const u64 vm = vmask[b * 16 + w];
        u64 supp = ~vm;
        u64 rwA[16], rwB[16];
#pragma unroll
        for (int q = 0; q < 16; ++q) rwA[q] = sm.sM[q * 16 + w];
        for (int wb = 0; wb < 16; ++wb) {
            u64 cur = __shfl(supp, wb, 64);
#pragma unroll
            for (int c4 = 0; c4 < 4; ++c4) {
                const int rn = wb * 64 + (c4 + 1) * 16;
                if (rn < 1024) {
#pragma unroll
                    for (int q = 0; q < 16; ++q) rwB[q] = sm.sM[(rn + q) * 16 + w];
                }
                u64 rc[16];
#pragma unroll
                for (int q = 0; q < 16; ++q) rc[q] = __shfl(rwA[q], wb, 64);
                u64 ar0 = rc[0] | rc[4] | rc[8]  | rc[12];
                u64 ar1 = rc[1] | rc[5] | rc[9]  | rc[13];
                u64 ar2 = rc[2] | rc[6] | rc[10] | rc[14];
                u64 ar3 = rc[3] | rc[7] | rc[11] | rc[15];
                const u32 intra = (u32)(((ar0 | ar1) | (ar2 | ar3)) >> (c4 * 16)) & 0xFFFFu;
                const u32 actm  = (~(u32)(cur >> (c4 * 16))) & 0xFFFFu;
                if (intra == 0u || actm == 0u) {
                    u64 s0 = 0, s1 = 0, s2 = 0, s3 = 0;
                    u64 c0 = 0, c1 = 0, c2 = 0, c3 = 0;
#pragma unroll
                    for (int q = 0; q < 16; q += 4) {
                        const u64 m0 = ((actm >> (q + 0)) & 1u) ? ~0ull : 0ull;
                        const u64 m1 = ((actm >> (q + 1)) & 1u) ? ~0ull : 0ull;
                        const u64 m2 = ((actm >> (q + 2)) & 1u) ? ~0ull : 0ull;
                        const u64 m3 = ((actm >> (q + 3)) & 1u) ? ~0ull : 0ull;
                        s0 |= rwA[q + 0] & m0;  c0 |= rc[q + 0] & m0;
                        s1 |= rwA[q + 1] & m1;  c1 |= rc[q + 1] & m1;
                        s2 |= rwA[q + 2] & m2;  c2 |= rc[q + 2] & m2;
                        s3 |= rwA[q + 3] & m3;  c3 |= rc[q + 3] & m3;
                    }
                    supp |= (s0 | s1) | (s2 | s3);
                    cur  |= (c0 | c1) | (c2 | c3);
                } else {
#pragma unroll
                    for (int q = 0; q < 16; ++q) {
                        const int ii = c4 * 16 + q;
                        const bool act = ((cur >> ii) & 1ull) == 0ull;
                        supp = act ? (supp | rwA[q]) : supp;
                        cur  = act ? (cur  | rc[q])  : cur;
                    }
                }
#pragma unroll
                for (int q = 0; q < 16; ++q) rwA[q] = rwB[q];
            }
        }
        sm.kw[w] = vm & ~supp;
    }
    __syncthreads();
    if (tid == 0) {
        int acc = 0;
        for (int w = 0; w < 16; ++w) { sm.wpfx[w] = acc; acc += __popcll(sm.kw[w]); }
        sm.wpfx[16] = acc;
    }
    __syncthreads();
    for (int r = tid; r < TOPK; r += stride) {
        int w = r >> 6, bp = r & 63;
        if ((sm.kw[w] >> bp) & 1ull) {
            int pos = sm.wpfx[w] + __popcll(sm.kw[w] & ((1ull << bp) - 1ull));
            if (pos < MAXDET) {
                float4 bx = box4[b * TOPK + r];
                float s = score[b * TOPK + r];
                float c = cls[b * TOPK + r];
                sm.sdet[pos * 6 + 0] = bx.x;
                sm.sdet[pos * 6 + 1] = bx.y;
                sm.sdet[pos * 6 + 2] = bx.z;
                sm.sdet[pos * 6 + 3] = bx.w;
                sm.sdet[pos * 6 + 4] = s;
                sm.sdet[pos * 6 + 5] = c;
                float term = (fabsf(bx.x - bx.z) + fabsf(bx.y - bx.w)) * s;
                atomicAdd(&sm.s_sum, term);
                if (pos == 0) sm.s_max = s;
            }
        }
    }
    __syncthreads();
    if (tid == 0) {
        int n = sm.wpfx[16]; if (n > MAXDET) n = MAXDET;
        float wh = (n > 0) ? (sm.s_sum / (2.0f * (float)n)) : 0.0f;
        atomicAdd(&out[0], sm.s_max / (float)BATCH);
        atomicAdd(&out[1], wh / (float)BATCH);
    }
    if (b == 2) {
        for (int t = tid; t < MAXDET * 6; t += stride) out[2 + t] = sm.sdet[t];
    }
}

// ---------------------------------------------------------------------------
// Cooperative pipeline: select (16 blocks) -> grid.sync -> IoU (256 blocks,
// block = (batch, 64-row stripe), sbx staged once) -> grid.sync -> NMS
// (16 blocks). Eliminates 2 kernel launches. __threadfence before each sync
// for cross-XCD visibility of boxoff4 / M.
// ---------------------------------------------------------------------------
__global__ __launch_bounds__(1024) void coop_pipeline(const u64* __restrict__ keys,
                                                      const float* __restrict__ in,
                                                      float4* __restrict__ box4,
                                                      float4* __restrict__ boxoff4,
                                                      float* __restrict__ score,
                                                      float* __restrict__ cls,
                                                      u64* __restrict__ vmask,
                                                      u64* __restrict__ M,
                                                      float* __restrict__ out) {
    __shared__ SmemU u;
    cooperative_groups::grid_group grid = cooperative_groups::this_grid();
    const int tid = threadIdx.x;

    // ---- phase S ----
    if (blockIdx.x < BATCH)
        dev_select(blockIdx.x, tid, u.s, keys, in, box4, boxoff4, score, cls, vmask);
    __threadfence();
    grid.sync();                       // also block-syncs: u.s dead before u.i reuse

    // ---- phase I ----
    {
        const int bb = blockIdx.x >> 4;          // batch
        const int rquad = blockIdx.x & 15;       // 64-row stripe; tw == rquad
        const int jmin = rquad << 6;
        for (int t = jmin + tid; t < TOPK; t += 1024) u.i.sbx[t] = boxoff4[bb * TOPK + t];
        __syncthreads();
        const int wv = tid >> 6, lane = tid & 63;
#pragma unroll
        for (int s = 0; s < 4; ++s) {
            const int i = (rquad << 6) + (s << 4) + wv;
            const float4 A = u.i.sbx[i];
            const float areaA = (A.z - A.x) * (A.w - A.y);
            u64 myword = 0ull;
            for (int t = rquad; t < 16; ++t) {
                int j = (t << 6) | lane;
                float4 Bx = u.i.sbx[j];
                float lx = fmaxf(A.x, Bx.x), ly = fmaxf(A.y, Bx.y);
                float rx = fminf(A.z, Bx.z), ry = fminf(A.w, Bx.w);
                float iw = fmaxf(rx - lx, 0.0f), ih = fmaxf(ry - ly, 0.0f);
                float inter = iw * ih;
                float areaB = (Bx.z - Bx.x) * (Bx.w - Bx.y);
                float iou = inter / (areaA + areaB - inter + 1e-7f);
                bool pred = (iou > IOU_T) && (j > i);
                u64 bal = __ballot(pred);
                if (lane == t) myword = bal;
            }
            if (lane < 16) M[((size_t)bb * TOPK + i) * 16 + lane] = myword;  // lanes<tw: 0
        }
    }
    __threadfence();
    grid.sync();

    // ---- phase N ----
    if (blockIdx.x < BATCH)
        dev_nms(blockIdx.x, tid, 1024, u.n, M, vmask, box4, score, cls, out);
}

// ---------------------------------------------------------------------------
// Fallback standalone kernels (proven 4-launch path) if coop unsupported.
// ---------------------------------------------------------------------------
__global__ __launch_bounds__(1024) void select_topk_k(const u64* __restrict__ keys,
                                                      const float* __restrict__ in,
                                                      float4* __restrict__ box4,
                                                      float4* __restrict__ boxoff4,
                                                      float* __restrict__ score,
                                                      float* __restrict__ cls,
                                                      u64* __restrict__ vmask) {
    __shared__ SmemS sm;
    dev_select(blockIdx.x, threadIdx.x, sm, keys, in, box4, boxoff4, score, cls, vmask);
}

__global__ __launch_bounds__(256) void iou_mask(const float4* __restrict__ boxoff4,
                                                u64* __restrict__ M) {
    __shared__ float4 sbx[TOPK];
    const int b = blockIdx.x >> 8;
    const int rb = blockIdx.x & 255;
    const int i = (rb << 2) | (threadIdx.x >> 6);
    const int lane = threadIdx.x & 63;
    const int tw = rb >> 4;
    const int jmin = tw << 6;
    for (int t = jmin + threadIdx.x; t < TOPK; t += 256) sbx[t] = boxoff4[b * TOPK + t];
    __syncthreads();
    const float4 A = sbx[i];
    const float areaA = (A.z - A.x) * (A.w - A.y);
    u64 myword = 0ull;
#pragma unroll 4
    for (int t = tw; t < 16; ++t) {
        int j = (t << 6) | lane;
        float4 Bx = sbx[j];
        float lx = fmaxf(A.x, Bx.x), ly = fmaxf(A.y, Bx.y);
        float rx = fminf(A.z, Bx.z), ry = fminf(A.w, Bx.w);
        float iw = fmaxf(rx - lx, 0.0f), ih = fmaxf(ry - ly, 0.0f);
        float inter = iw * ih;
        float areaB = (Bx.z - Bx.x) * (Bx.w - Bx.y);
        float iou = inter / (areaA + areaB - inter + 1e-7f);
        bool pred = (iou > IOU_T) && (j > i);
        u64 bal = __ballot(pred);
        if (lane == t) myword = bal;
    }
    if (lane < 16) M[((size_t)b * TOPK + i) * 16 + lane] = myword;
}

__global__ __launch_bounds__(512) void nms_finalize_k(const u64* __restrict__ M,
                                                      const u64* __restrict__ vmask,
                                                      const float4* __restrict__ box4,
                                                      const float* __restrict__ score,
                                                      const float* __restrict__ cls,
                                                      float* __restrict__ out) {
    __shared__ SmemN sm;
    dev_nms(blockIdx.x, threadIdx.x, 512, sm, M, vmask, box4, score, cls, out);
}

extern "C" void kernel_launch(void* const* d_in, const int* in_sizes, int n_in,
                              void* d_out, int out_size, void* d_ws, size_t ws_size,
                              hipStream_t stream) {
    const float* in = (const float*)d_in[0];
    float* out = (float*)d_out;
    char* ws = (char*)d_ws;

    u64*    keys     = (u64*)   (ws + 0);                       // 3,225,600
    float4* boxoff4  = (float4*)(ws + 3225600);                 //   262,144
    float4* box4     = (float4*)(ws + 3487744);                 //   262,144
    float*  score    = (float*) (ws + 3749888);                 //    65,536
    float*  cls      = (float*) (ws + 3815424);                 //    65,536
    u64*    vmask    = (u64*)   (ws + 3880960);                 //     2,048
    u64*    M        = (u64*)   (ws + 3883008);                 // 2,097,152

    static int s_coop = -1;
    if (s_coop < 0) {
        int dev = 0; hipGetDevice(&dev);
        int v = 0;
        hipDeviceGetAttribute(&v, hipDeviceAttributeCooperativeLaunch, dev);
        s_coop = v;
    }

    score_kernel<<<2100, 256, 0, stream>>>(in, keys, out);

    if (s_coop) {
        void* args[] = { (void*)&keys, (void*)&in, (void*)&box4, (void*)&boxoff4,
                         (void*)&score, (void*)&cls, (void*)&vmask, (void*)&M,
                         (void*)&out };
        hipLaunchCooperativeKernel((const void*)coop_pipeline, dim3(256), dim3(1024),
                                   args, 0, stream);
    } else {
        select_topk_k<<<BATCH, 1024, 0, stream>>>(keys, in, box4, boxoff4, score, cls, vmask);
        iou_mask<<<BATCH * 256, 256, 0, stream>>>(boxoff4, M);
        nms_finalize_k<<<BATCH, 512, 0, stream>>>(M, vmask, box4, score, cls, out);
    }
}

// Round 9
// 277.326 us; speedup vs baseline: 1.7462x; 1.7462x over previous
//
#include <hip/hip_runtime.h>
#include <hip/hip_bf16.h>

typedef unsigned long long u64;
typedef unsigned int u32;

#define BATCH 16
#define NANCH 25200
#define NCLS 80
#define NFEAT 85
#define TOPK 1024
#define MAXDET 300
#define CONF_T 0.25f
#define IOU_T 0.45f
#define MAX_WH 7680.0f

#define GRP 16                    // anchors per wave-group
#define GRPB (GRP * NFEAT * 4)    // 5440 B, 16B-aligned (16*340)
#define NGRP (NANCH / GRP)        // 1575 exact (25200 = 1575*16)

// async 16B global->LDS (gfx950). LDS dest is wave-uniform base + lane*16;
// divergent-exec tail proven safe R0-R8 (absmax 0.0 across runs).
__device__ __forceinline__ void gload_lds16(const void* g, void* l) {
    __builtin_amdgcn_global_load_lds(
        (const __attribute__((address_space(1))) unsigned int*)g,
        (__attribute__((address_space(3))) unsigned int*)l, 16, 0, 0);
}

// ---------------------------------------------------------------------------
// K1: per-anchor score + 64-bit sort key.
// R9: DOUBLE-BUFFERED per-wave DMA (T3/T4 pattern). R8 model: score = 44us
// vs 22us BW floor -- the old issue-6 -> vmcnt(0) -> compute loop has zero
// overlap between a wave's groups. Now: two 5440B slices/wave; issue next
// group's 6 chunks into the other slice BEFORE waiting vmcnt(6) (= the 6
// oldest, i.e. current slice complete). Every wave keeps 6-12KB in flight.
// lgkmcnt(0) before re-staging a slice (WAR vs prior ds_reads); manual
// counted vmcnt is authoritative (compiler does not auto-wait for
// global_load_lds before ds_read).
// key = (ordered_score_bits << 32) | ((idx ^ 0xFFFF) << 8) | class
// ---------------------------------------------------------------------------
__global__ __launch_bounds__(256) void score_kernel(const float* __restrict__ in,
                                                    u64* __restrict__ keys,
                                                    float* __restrict__ out) {
    __shared__ char lds[8 * GRPB];   // 43520 B: 2 slices per wave x 4 waves
    const int tid = threadIdx.x, wv = tid >> 6, lane = tid & 63;
    if (blockIdx.x == 0 && tid == 0) { out[0] = 0.0f; out[1] = 0.0f; }
    char* sl0 = lds + wv * (2 * GRPB);
    char* sl1 = sl0 + GRPB;
    const int a = lane >> 2, q = lane & 3;
    const int wave_id = (blockIdx.x << 2) | wv;
    const int nwaves = gridDim.x << 2;                 // 3072
    const int total = BATCH * NGRP;                    // 25200

    char* cur = sl0;
    char* nxt = sl1;
    // prologue: stage first group into cur
    {
        const int g = wave_id;                         // < 3072 < total always
        const int b = g / NGRP;
        const int a0 = (g - b * NGRP) * GRP;
        const char* gbase = (const char*)(in + ((size_t)b * NANCH + a0) * NFEAT);
#pragma unroll
        for (int r = 0; r < 6; ++r) {
            const int myb = (r << 10) + lane * 16;
            if (myb < GRPB) gload_lds16(gbase + myb, cur + (r << 10));
        }
    }
    for (int g = wave_id; g < total; g += nwaves) {
        const int gn = g + nwaves;
        if (gn < total) {
            // stage next group into nxt (its prior ds_reads retired: data
            // consumed 2 iters ago; lgkmcnt(0) makes the WAR explicit).
            const int bn = gn / NGRP;
            const int an0 = (gn - bn * NGRP) * GRP;
            const char* gb = (const char*)(in + ((size_t)bn * NANCH + an0) * NFEAT);
            asm volatile("s_waitcnt lgkmcnt(0)" ::: "memory");
#pragma unroll
            for (int r = 0; r < 6; ++r) {
                const int myb = (r << 10) + lane * 16;
                if (myb < GRPB) gload_lds16(gb + myb, nxt + (r << 10));
            }
            asm volatile("s_waitcnt vmcnt(6)" ::: "memory");   // cur ready
        } else {
            asm volatile("s_waitcnt vmcnt(0)" ::: "memory");   // drain last
        }
        __builtin_amdgcn_sched_barrier(0);             // no hoist past waits
        const int b = g / NGRP;
        const int a0 = (g - b * NGRP) * GRP;
        const float* myp = (const float*)cur + a * NFEAT;
        float obj = myp[4];
        float best = -1e30f;
        int bj = 0;
#pragma unroll
        for (int k = 0; k < 20; ++k) {
            float v = myp[5 + q * 20 + k] * obj;
            if (v > best) { best = v; bj = q * 20 + k; }   // first-occurrence argmax
        }
#pragma unroll
        for (int d = 1; d < 4; d <<= 1) {                  // reduce across 4-lane group
            float ob = __shfl_xor(best, d, 64);
            int oj = __shfl_xor(bj, d, 64);
            if (ob > best || (ob == best && oj < bj)) { best = ob; bj = oj; }
        }
        if (q == 0) {
            bool valid = (obj > CONF_T) && (best > CONF_T);
            float sc = valid ? best : -1.0f;
            u32 sb = __float_as_uint(sc);
            u32 ord = sb ^ ((sb & 0x80000000u) ? 0xFFFFFFFFu : 0x80000000u);
            int idx = a0 + a;
            keys[(size_t)b * NANCH + idx] =
                ((u64)ord << 32) | ((u64)((u32)(idx ^ 0xFFFF) & 0xFFFFu) << 8) | (u64)bj;
        }
        char* t = cur; cur = nxt; nxt = t;             // swap slices
    }
}

// ---------------------------------------------------------------------------
// K2: exact top-1024 per batch (R7-proven). Register ballot-histogram over
// the provable 18-bin support {0x407} U [0xBE8,0xBF7], >/== compaction
// (A/B split preserves exactness on overflow), hybrid bitonic sort,
// extraction.
// ---------------------------------------------------------------------------
__global__ __launch_bounds__(1024) void select_topk(const u64* __restrict__ keys,
                                                    const float* __restrict__ in,
                                                    float4* __restrict__ box4,
                                                    float4* __restrict__ boxoff4,
                                                    float* __restrict__ score,
                                                    float* __restrict__ cls,
                                                    u64* __restrict__ vmask) {
    const int b = blockIdx.x, tid = threadIdx.x;
    const int lane = tid & 63, wv = tid >> 6;
    const u64* kb = keys + (size_t)b * NANCH;
    const ulonglong2* kb2 = (const ulonglong2*)kb;    // 12600 pairs, 16B-aligned
    __shared__ u32 wcnt[16][17];
    __shared__ u32 tot[17];
    __shared__ u32 s_prefix12, s_cnt;
    __shared__ u64 buf[2048];

    // ---- phase 1: register ballot-histogram over the 18-bin support ----
    u32 myc = 0;                       // lane k (k<17) accumulates compact bin k
    for (int n = tid; n < 12600; n += 1024) {     // 25200 keys, 2/thread
        ulonglong2 kk = kb2[n];
        u32 b0 = (u32)(kk.x >> 52);
        u32 b1 = (u32)(kk.y >> 52);
        u32 c0 = (b0 == 0x407u) ? 16u : (b0 - 0xBE8u);   // 0..15 valid, 16 invalid
        u32 c1 = (b1 == 0x407u) ? 16u : (b1 - 0xBE8u);
#pragma unroll
        for (u32 k = 0; k < 17; ++k) {
            u64 m0 = __ballot(c0 == k);
            u64 m1 = __ballot(c1 == k);
            if (lane == (int)k) myc += (u32)__popcll(m0) + (u32)__popcll(m1);
        }
    }
    if (lane < 17) wcnt[wv][lane] = myc;
    if (tid == 0) s_cnt = 0u;
    __syncthreads();
    if (tid < 17) {
        u32 t = 0;
#pragma unroll
        for (int w = 0; w < 16; ++w) t += wcnt[w][tid];
        tot[tid] = t;
    }
    __syncthreads();
    if (tid == 0) {
        u32 acc = 0; u32 p = 0x407u;
        for (int k = 15; k >= 0; --k) {
            if (acc < (u32)TOPK && acc + tot[k] >= (u32)TOPK) p = 0xBE8u + (u32)k;
            acc += tot[k];
        }
        if (acc < (u32)TOPK) p = 0x407u;   // crossing falls in the invalid bin
        s_prefix12 = p;
    }
    __syncthreads();
    const u32 p12 = s_prefix12;
    // Pass A: strictly greater 12-bit prefix (count < 1024 by construction).
    for (int n = tid; n < 12600; n += 1024) {
        ulonglong2 kk = kb2[n];
        if ((u32)(kk.x >> 52) > p12) {
            u32 pos = atomicAdd(&s_cnt, 1u);
            if (pos < 2048u) buf[pos] = kk.x;
        }
        if ((u32)(kk.y >> 52) > p12) {
            u32 pos = atomicAdd(&s_cnt, 1u);
            if (pos < 2048u) buf[pos] = kk.y;
        }
    }
    __syncthreads();
    // Pass B: equal prefix (~1300 for this distribution; fits 2048; on
    // overflow only ==-class keys are dropped -> exact top-k preserved).
    for (int n = tid; n < 12600; n += 1024) {
        ulonglong2 kk = kb2[n];
        if ((u32)(kk.x >> 52) == p12) {
            u32 pos = atomicAdd(&s_cnt, 1u);
            if (pos < 2048u) buf[pos] = kk.x;
        }
        if ((u32)(kk.y >> 52) == p12) {
            u32 pos = atomicAdd(&s_cnt, 1u);
            if (pos < 2048u) buf[pos] = kk.y;
        }
    }
    __syncthreads();
    u32 cnt = s_cnt; if (cnt > 2048u) cnt = 2048u;
    for (int n = (int)cnt + tid; n < 2048; n += 1024) buf[n] = 0ull;
    __syncthreads();

    // ---- hybrid bitonic sort, descending, 2048 u64 keys ----
    const int base = wv * 128;
    u64 r0 = buf[base + lane], r1 = buf[base + 64 + lane];
    for (int k2 = 2; k2 <= 128; k2 <<= 1) {
        const bool d0 = (((base + lane) & k2) == 0);
        const bool d1 = (((base + 64 + lane) & k2) == 0);
        for (int jj = (k2 >> 1); jj >= 1; jj >>= 1) {
            if (jj == 64) {
                u64 mx = r0 > r1 ? r0 : r1, mn = r0 > r1 ? r1 : r0;
                r0 = d0 ? mx : mn; r1 = d0 ? mn : mx;
            } else {
                const bool up = (lane & jj) != 0;
                u64 v0 = __shfl_xor(r0, jj, 64);
                u64 v1 = __shfl_xor(r1, jj, 64);
                const bool km0 = (d0 != up), km1 = (d1 != up);
                r0 = km0 ? (r0 > v0 ? r0 : v0) : (r0 < v0 ? r0 : v0);
                r1 = km1 ? (r1 > v1 ? r1 : v1) : (r1 < v1 ? r1 : v1);
            }
        }
    }
    for (int k2 = 256; k2 <= 2048; k2 <<= 1) {
        buf[base + lane] = r0; buf[base + 64 + lane] = r1;
        __syncthreads();
        for (int jj = (k2 >> 1); jj >= 128; jj >>= 1) {
            int i = ((tid & ~(jj - 1)) << 1) | (tid & (jj - 1));
            int part = i | jj;
            u64 a = buf[i], c = buf[part];
            bool sw = ((i & k2) == 0) ? (a < c) : (a > c);
            if (sw) { buf[i] = c; buf[part] = a; }
            __syncthreads();
        }
        r0 = buf[base + lane]; r1 = buf[base + 64 + lane];
        const bool d0 = (((base + lane) & k2) == 0);   // == d1 for k2 >= 256
        for (int jj = 64; jj >= 1; jj >>= 1) {
            if (jj == 64) {
                u64 mx = r0 > r1 ? r0 : r1, mn = r0 > r1 ? r1 : r0;
                r0 = d0 ? mx : mn; r1 = d0 ? mn : mx;
            } else {
                const bool up = (lane & jj) != 0;
                u64 v0 = __shfl_xor(r0, jj, 64);
                u64 v1 = __shfl_xor(r1, jj, 64);
                const bool km = (d0 != up);
                r0 = km ? (r0 > v0 ? r0 : v0) : (r0 < v0 ? r0 : v0);
                r1 = km ? (r1 > v1 ? r1 : v1) : (r1 < v1 ? r1 : v1);
            }
        }
    }
    buf[base + lane] = r0; buf[base + 64 + lane] = r1;
    __syncthreads();

    // Output rank tid (0..1023). cnt >= 1024 always, so buf[tid] is real.
    u64 k = buf[tid];
    u32 ord = (u32)(k >> 32);
    u32 sb = (ord & 0x80000000u) ? (ord ^ 0x80000000u) : ~ord;
    float sc = __uint_as_float(sb);
    int idx = (int)((((u32)(k >> 8)) & 0xFFFFu) ^ 0xFFFFu);
    int j = (int)(k & 0xFFu);
    const float* pr = in + ((size_t)b * NANCH + idx) * NFEAT;
    float cx = pr[0], cy = pr[1], ww = pr[2], hh = pr[3];
    float x1 = cx - ww / 2.0f, y1 = cy - hh / 2.0f;
    float x2 = cx + ww / 2.0f, y2 = cy + hh / 2.0f;
    float c = (float)j;
    float cm = c * MAX_WH;
    box4[b * TOPK + tid]    = make_float4(x1, y1, x2, y2);
    boxoff4[b * TOPK + tid] = make_float4(x1 + cm, y1 + cm, x2 + cm, y2 + cm);
    score[b * TOPK + tid] = sc;
    cls[b * TOPK + tid] = c;
    u64 bal = __ballot(sc > 0.0f);
    if ((tid & 63) == 0) vmask[b * 16 + (tid >> 6)] = bal;
}

// ---------------------------------------------------------------------------
// K3: suppression bitmask (4096 blocks -- full-chip parallel, ~5us). Upper
// triangle only; stages only sbx[jmin..1023]. In-block IoU is ruled out
// (R2/R8 model: IEEE-div chains cost ~40us on 16 CUs vs ~5us here).
// ---------------------------------------------------------------------------
__global__ __launch_bounds__(256) void iou_mask(const float4* __restrict__ boxoff4,
                                                u64* __restrict__ M) {
    __shared__ float4 sbx[TOPK];   // 16 KB (entries < jmin left unread)
    const int b = blockIdx.x >> 8;
    const int rb = blockIdx.x & 255;
    const int i = (rb << 2) | (threadIdx.x >> 6);
    const int lane = threadIdx.x & 63;
    const int tw = rb >> 4;          // == i >> 6 for all 4 rows of this block
    const int jmin = tw << 6;
    for (int t = jmin + threadIdx.x; t < TOPK; t += 256) sbx[t] = boxoff4[b * TOPK + t];
    __syncthreads();
    const float4 A = sbx[i];
    const float areaA = (A.z - A.x) * (A.w - A.y);
    u64 myword = 0ull;
#pragma unroll 4
    for (int t = tw; t < 16; ++t) {
        int j = (t << 6) | lane;
        float4 Bx = sbx[j];
        float lx = fmaxf(A.x, Bx.x), ly = fmaxf(A.y, Bx.y);
        float rx = fminf(A.z, Bx.z), ry = fminf(A.w, Bx.w);
        float iw = fmaxf(rx - lx, 0.0f), ih = fmaxf(ry - ly, 0.0f);
        float inter = iw * ih;
        float areaB = (Bx.z - Bx.x) * (Bx.w - Bx.y);
        float iou = inter / (areaA + areaB - inter + 1e-7f);
        bool pred = (iou > IOU_T) && (j > i);
        u64 bal = __ballot(pred);
        if (lane == t) myword = bal;
    }
    if (lane < 16) M[((size_t)b * TOPK + i) * 16 + lane] = myword;   // lanes < tw store 0
}

// ---------------------------------------------------------------------------
// K4: fused sequential NMS + finalize (OR-tree fast path per 16-row group).
// ---------------------------------------------------------------------------
__global__ __launch_bounds__(512) void nms_finalize(const u64* __restrict__ M,
                                                    const u64* __restrict__ vmask,
                                                    const float4* __restrict__ box4,
                                                    const float* __restrict__ score,
                                                    const float* __restrict__ cls,
                                                    float* __restrict__ out) {
    __shared__ u64 sM[TOPK * 16];     // 131072 B
    __shared__ u64 kw[16];
    __shared__ int wpfx[17];
    __shared__ float sdet[MAXDET * 6];
    __shared__ float s_sum, s_max;
    const int b = blockIdx.x, tid = threadIdx.x;
    {
        const ulonglong2* Ms = (const ulonglong2*)(M + (size_t)b * TOPK * 16);
        ulonglong2* Ldst = (ulonglong2*)sM;
#pragma unroll 4
        for (int t = tid; t < TOPK * 8; t += 512) Ldst[t] = Ms[t];
    }
    for (int t = tid; t < MAXDET * 6; t += 512) sdet[t] = 0.0f;
    if (tid == 0) { s_sum = 0.0f; s_max = 0.0f; }
    __syncthreads();
    if (tid < 16) {
        const int w = tid;
        const u64 vm = vmask[b * 16 + w];
        u64 supp = ~vm;
        u64 rwA[16], rwB[16];
#pragma unroll
        for (int q = 0; q < 16; ++q) rwA[q] = sM[q * 16 + w];   // rows 0..15
        for (int wb = 0; wb < 16; ++wb) {
            u64 cur = __shfl(supp, wb, 64);
#pragma unroll
            for (int c4 = 0; c4 < 4; ++c4) {
                const int rn = wb * 64 + (c4 + 1) * 16;   // prefetch next 16 rows
                if (rn < 1024) {
#pragma unroll
                    for (int q = 0; q < 16; ++q) rwB[q] = sM[(rn + q) * 16 + w];
                }
                u64 rc[16];
#pragma unroll
                for (int q = 0; q < 16; ++q) rc[q] = __shfl(rwA[q], wb, 64);
                u64 ar0 = rc[0] | rc[4] | rc[8]  | rc[12];
                u64 ar1 = rc[1] | rc[5] | rc[9]  | rc[13];
                u64 ar2 = rc[2] | rc[6] | rc[10] | rc[14];
                u64 ar3 = rc[3] | rc[7] | rc[11] | rc[15];
                const u32 intra = (u32)(((ar0 | ar1) | (ar2 | ar3)) >> (c4 * 16)) & 0xFFFFu;
                const u32 actm  = (~(u32)(cur >> (c4 * 16))) & 0xFFFFu;
                if (intra == 0u || actm == 0u) {
                    u64 s0 = 0, s1 = 0, s2 = 0, s3 = 0;
                    u64 c0 = 0, c1 = 0, c2 = 0, c3 = 0;
#pragma unroll
                    for (int q = 0; q < 16; q += 4) {
                        const u64 m0 = ((actm >> (q + 0)) & 1u) ? ~0ull : 0ull;
                        const u64 m1 = ((actm >> (q + 1)) & 1u) ? ~0ull : 0ull;
                        const u64 m2 = ((actm >> (q + 2)) & 1u) ? ~0ull : 0ull;
                        const u64 m3 = ((actm >> (q + 3)) & 1u) ? ~0ull : 0ull;
                        s0 |= rwA[q + 0] & m0;  c0 |= rc[q + 0] & m0;
                        s1 |= rwA[q + 1] & m1;  c1 |= rc[q + 1] & m1;
                        s2 |= rwA[q + 2] & m2;  c2 |= rc[q + 2] & m2;
                        s3 |= rwA[q + 3] & m3;  c3 |= rc[q + 3] & m3;
                    }
                    supp |= (s0 | s1) | (s2 | s3);
                    cur  |= (c0 | c1) | (c2 | c3);
                } else {
#pragma unroll
                    for (int q = 0; q < 16; ++q) {
                        const int ii = c4 * 16 + q;            // compile-time 0..63
                        const bool act = ((cur >> ii) & 1ull) == 0ull;
                        supp = act ? (supp | rwA[q]) : supp;
                        cur  = act ? (cur  | rc[q])  : cur;
                    }
                }
#pragma unroll
                for (int q = 0; q < 16; ++q) rwA[q] = rwB[q];
            }
        }
        kw[w] = vm & ~supp;
    }
    __syncthreads();
    if (tid == 0) {
        int acc = 0;
        for (int w = 0; w < 16; ++w) { wpfx[w] = acc; acc += __popcll(kw[w]); }
        wpfx[16] = acc;
    }
    __syncthreads();
    for (int r = tid; r < TOPK; r += 512) {
        int w = r >> 6, bp = r & 63;
        if ((kw[w] >> bp) & 1ull) {
            int pos = wpfx[w] + __popcll(kw[w] & ((1ull << bp) - 1ull));
            if (pos < MAXDET) {
                float4 bx = box4[b * TOPK + r];
                float s = score[b * TOPK + r];
                float c = cls[b * TOPK + r];
                sdet[pos * 6 + 0] = bx.x;
                sdet[pos * 6 + 1] = bx.y;
                sdet[pos * 6 + 2] = bx.z;
                sdet[pos * 6 + 3] = bx.w;
                sdet[pos * 6 + 4] = s;
                sdet[pos * 6 + 5] = c;
                float term = (fabsf(bx.x - bx.z) + fabsf(bx.y - bx.w)) * s;
                atomicAdd(&s_sum, term);
                if (pos == 0) s_max = s;
            }
        }
    }
    __syncthreads();
    if (tid == 0) {
        int n = wpfx[16]; if (n > MAXDET) n = MAXDET;
        float wh = (n > 0) ? (s_sum / (2.0f * (float)n)) : 0.0f;
        atomicAdd(&out[0], s_max / (float)BATCH);
        atomicAdd(&out[1], wh / (float)BATCH);
    }
    if (b == 2) {
        for (int t = tid; t < MAXDET * 6; t += 512) out[2 + t] = sdet[t];
    }
}

extern "C" void kernel_launch(void* const* d_in, const int* in_sizes, int n_in,
                              void* d_out, int out_size, void* d_ws, size_t ws_size,
                              hipStream_t stream) {
    const float* in = (const float*)d_in[0];
    float* out = (float*)d_out;
    char* ws = (char*)d_ws;

    u64*    keys     = (u64*)   (ws + 0);                       // 3,225,600
    float4* boxoff4  = (float4*)(ws + 3225600);                 //   262,144
    float4* box4     = (float4*)(ws + 3487744);                 //   262,144
    float*  score    = (float*) (ws + 3749888);                 //    65,536
    float*  cls      = (float*) (ws + 3815424);                 //    65,536
    u64*    vmask    = (u64*)   (ws + 3880960);                 //     2,048
    u64*    M        = (u64*)   (ws + 3883008);                 // 2,097,152

    // 768 blocks = 3 blocks/CU (43.5KB LDS each) = 3072 waves, 8-9 groups/wave.
    score_kernel<<<768, 256, 0, stream>>>(in, keys, out);
    select_topk<<<BATCH, 1024, 0, stream>>>(keys, in, box4, boxoff4, score, cls, vmask);
    iou_mask<<<BATCH * 256, 256, 0, stream>>>(boxoff4, M);
    nms_finalize<<<BATCH, 512, 0, stream>>>(M, vmask, box4, score, cls, out);
}